// Round 11
// baseline (1655.111 us; speedup 1.0000x reference)
//
#include <hip/hip_runtime.h>
#include <hip/hip_bf16.h>
#include <math.h>

// Problem constants (fixed by setup_inputs)
#define BSZ    8
#define TSTEPS 10
#define FLEN   10
#define HID    64
#define HW     4096                 // 64*64
#define IMG    (HID * HW)           // 262144
#define OC4    (4 * HID)            // 256 gate channels
#define PADW   66
#define PPIX   (PADW * PADW)        // 4356
#define PADIMG (PPIX * HID)         // padded NHWC plane per batch
#define PADSZ  (BSZ * PADIMG)       // 2230272 bf16 elems per buffer
#define SB     (BSZ * IMG)          // 2097152 floats (one c state)
#define KT_E0  640                  // enc0: 1 x-im2col chunk + 9 h chunks
#define KT_STD 1152                 // 9 x chunks + 9 h chunks

typedef __attribute__((ext_vector_type(8))) short bf16x8;
typedef __attribute__((ext_vector_type(4))) float f32x4;

__device__ __forceinline__ float sigmoidf_(float x) {
    return 1.0f / (1.0f + __expf(-x));
}
__device__ __forceinline__ float tanh_fast(float x) {
    float e = __expf(2.0f * x);
    return 1.0f - 2.0f / (e + 1.0f);     // exact at +-inf saturation
}
__device__ __forceinline__ float bf2f(short u) {
    union { unsigned u; float f; } cv;
    cv.u = ((unsigned)(unsigned short)u) << 16;
    return cv.f;
}
__device__ __forceinline__ short f2bf(float x) {
    __hip_bfloat16 h = __float2bfloat16(x);
    union { __hip_bfloat16 h; short s; } cv; cv.h = h;
    return cv.s;
}

// ---------------------------------------------------------------------------
// Weight reorder -> Bw[oc'=hid*4+gate][k], bf16. Source oc = gate*64+hid.
// icx==1 (enc0): chunk0 = x-im2col taps (9 live of 64), chunks 1..9 = Wh taps.
// else: chunks 0..8 = Wx taps, 9..17 = Wh taps (64 ch each).
__global__ __launch_bounds__(256) void reorder_w(
    const float* __restrict__ Wx, int icx,
    const float* __restrict__ Wh, __hip_bfloat16* __restrict__ Bw, int ktot) {
    int ocp = blockIdx.x, hid = ocp >> 2, gate = ocp & 3;
    int oc = gate * 64 + hid;
    for (int k = threadIdx.x; k < ktot; k += 256) {
        int c = k >> 6, j = k & 63;
        float v;
        if (icx == 1) {
            if (c == 0) v = (j < 9) ? Wx[oc * 9 + j] : 0.0f;
            else        v = Wh[(oc * 64 + j) * 9 + (c - 1)];
        } else {
            if (c < 9)  v = Wx[(oc * 64 + j) * 9 + c];
            else        v = Wh[(oc * 64 + j) * 9 + (c - 9)];
        }
        Bw[ocp * ktot + k] = __float2bfloat16(v);
    }
}

// ---------------------------------------------------------------------------
// Pack Wc + bias -> wcb[hid*HW + p][8] bf16: [Wc g0..g3, bias g0..g3].
__global__ __launch_bounds__(256) void pack_wcb(
    const float* __restrict__ Wc, const float* __restrict__ bias,
    __hip_bfloat16* __restrict__ wcb) {
    int i = blockIdx.x * 256 + threadIdx.x;   // 0 .. HID*HW-1
    int hid = i >> 12, p = i & 4095;
    union { short s[8]; bf16x8 v; } u;
#pragma unroll
    for (int g = 0; g < 4; g++) {
        u.s[g]     = f2bf(Wc[(g * HID + hid) * HW + p]);
        u.s[4 + g] = f2bf(bias[(g * HID + hid) * HW + p]);
    }
    *(bf16x8*)&wcb[(size_t)i * 8] = u.v;
}

// ---------------------------------------------------------------------------
// im2col of x for ALL timesteps into padded NHWC bf16: ch 0..8 = 3x3 taps,
// ch 9..15 zero; ch 16..63 left as poison (only multiplied by zero weights).
// Covers the full 66x66 padded grid (ring written as zeros; never read anyway).
__global__ __launch_bounds__(256) void pack_x_all(
    const float* __restrict__ x, __hip_bfloat16* __restrict__ px_all) {
    int i = blockIdx.x * 256 + threadIdx.x;   // 0 .. 10*8*4356-1
    if (i >= TSTEPS * BSZ * PPIX) return;
    int t = i / (BSZ * PPIX);
    int rem = i - t * (BSZ * PPIX);
    int b = rem / PPIX;
    int pp = rem - b * PPIX;
    int y = pp / PADW, xx = pp - y * PADW;    // padded coords 0..65
    int oy = y - 1, ox = xx - 1;
    const float* xb = x + ((size_t)(b * TSTEPS + t)) * HW;
    bool interior = (oy >= 0 && oy < 64 && ox >= 0 && ox < 64);
    union { short s[16]; bf16x8 v[2]; } u;
#pragma unroll
    for (int tap = 0; tap < 9; tap++) {
        int yy = oy + tap / 3 - 1, xc = ox + tap % 3 - 1;
        float val = (interior && yy >= 0 && yy < 64 && xc >= 0 && xc < 64)
                        ? xb[yy * 64 + xc] : 0.0f;
        u.s[tap] = f2bf(val);
    }
#pragma unroll
    for (int tap = 9; tap < 16; tap++) u.s[tap] = 0;
    short* o = (short*)(px_all + (size_t)t * PADSZ + ((size_t)(b * PPIX + pp)) * HID);
    *(bf16x8*)&o[0] = u.v[0];
    *(bf16x8*)&o[8] = u.v[1];
}

// ---------------------------------------------------------------------------
struct CellArgs {
    const __hip_bfloat16* Bw;
    const __hip_bfloat16* src0;
    const __hip_bfloat16* src1;
    const __hip_bfloat16* wcb;
    float* cbuf;
    __hip_bfloat16* hout;
    int ktot;   // 640 or 1152
    int n0;     // 1 or 9
    int first;  // skip c read (h(-1)=c(-1)=0)
};

// Fused im2col-GEMM + LSTM cell. M=256 (oc'=hid*4+gate), N=32768 (px), K=ktot.
// 128oc x 64px tile, 4 waves (wave = 64oc x 32px, acc[4][2]).
// Round-11: FULL A+B double-buffer with counted vmcnt(6). r6's B-only
// prefetch was null because stage_A(kk)'s 4 loads were issued and then
// immediately waited on (vmcnt(2) covers only B) — every chunk exposed A's
// L2 round-trip. Now chunk kk+1's 6 loads (4 A + 2 B) are issued into the
// other buffer BEFORE waiting; vmcnt(6) confirms chunk kk (issued a full
// iteration ago, a whole compute phase to land) while kk+1's loads fly
// across the MFMAs. r1's full-dbuf attempt was confounded by the 196-VGPR
// fold poison — this is the clean test.
// Raw s_barrier (memory clobber): __syncthreads() would emit vmcnt(0) and
// drain the prefetch. Hazards: buffer cur^1's last readers (chunk kk-1's
// compute) finished before the previous trailing s_barrier, which precedes
// this iteration's stage issues — the same proven-safe ordering as r6.
// LDS 48 KB -> 3 blocks/CU cap (measured effective residency was ~2.6 at
// 32 KB, so minimal loss). VGPR must stay <=64 (r5 lesson; final_conv stays
// a separate kernel to protect regalloc).
// blockIdx.z selects one of two independent cell-steps (encoder pipelining).
// Epilogue: in-register cell update; h transposed through LDS -> coalesced
// 16B NHWC stores.
__global__ __launch_bounds__(256, 4) void gemm_cell_fused(CellArgs A0, CellArgs A1) {
    __shared__ short As[2][128 * 64];   // 2 x 16 KB
    __shared__ short Bs[2][64 * 64];    // 2 x 8 KB

    const bool z1 = (blockIdx.z != 0);
    const __hip_bfloat16* __restrict__ Bw   = z1 ? A1.Bw   : A0.Bw;
    const __hip_bfloat16* __restrict__ src0 = z1 ? A1.src0 : A0.src0;
    const __hip_bfloat16* __restrict__ src1 = z1 ? A1.src1 : A0.src1;
    const __hip_bfloat16* __restrict__ wcb  = z1 ? A1.wcb  : A0.wcb;
    float* __restrict__ cbuf                = z1 ? A1.cbuf : A0.cbuf;
    __hip_bfloat16* __restrict__ hout       = z1 ? A1.hout : A0.hout;
    const int ktot  = z1 ? A1.ktot  : A0.ktot;
    const int n0    = z1 ? A1.n0    : A0.n0;
    const int first = z1 ? A1.first : A0.first;

    const int tid  = threadIdx.x;
    const int lane = tid & 63;
    const int wave = tid >> 6;       // 0..3
    const int quad = lane >> 4;
    const int l15  = lane & 15;
    const int wr = wave >> 1;        // 0..1  (64-row oc' half)
    const int wc = wave & 1;         // 0..1  (32-col px half)
    const int px0 = blockIdx.x * 64;
    const int oc0 = blockIdx.y * 128;

    // A staging: 128 rows x 8 segs = 1024 tasks -> 4 rounds of 256.
    // B staging: 64 rows x 8 segs = 512 tasks -> 2 rounds of 256.
    int a_off[4], s_off[2];
#pragma unroll
    for (int it = 0; it < 4; it++) {
        int idx = it * 256 + tid;
        int rr = idx >> 3, seg = idx & 7;
        int segx = seg ^ (rr & 7);            // global-side swizzle
        a_off[it] = (oc0 + rr) * ktot + segx * 8;
    }
#pragma unroll
    for (int it = 0; it < 2; it++) {
        int idx = it * 256 + tid;
        int rr = idx >> 3, seg = idx & 7;
        int segx = seg ^ (rr & 7);
        int px = px0 + rr;
        int b = px >> 12, p = px & 4095, y = p >> 6, x = p & 63;
        s_off[it] = ((b * PADW + y + 1) * PADW + (x + 1)) * HID + segx * 8;
    }
    const int ldsbase = (tid & ~63) * 8;      // wave-uniform
    const int xa = l15 & 7;                   // read-side swizzle (= row&7)

    f32x4 acc[4][2] = {};
    const int nchunks = n0 + 9;

    auto stage_A = [&](int kk, int buf) {
        int ka = kk * 64;
#pragma unroll
        for (int it = 0; it < 4; it++)
            __builtin_amdgcn_global_load_lds(
                (const __attribute__((address_space(1))) void*)(Bw + a_off[it] + ka),
                (__attribute__((address_space(3))) void*)(&As[buf][it * 2048 + ldsbase]),
                16, 0, 0);
    };
    auto stage_B = [&](int kk, int buf) {
        const __hip_bfloat16* src;
        int tap;
        if (kk < n0) { src = src0; tap = (n0 == 1) ? 4 : kk; }
        else         { src = src1; tap = kk - n0; }
        int dd = ((tap / 3) - 1) * (PADW * HID) + ((tap % 3) - 1) * HID;
#pragma unroll
        for (int it = 0; it < 2; it++)
            __builtin_amdgcn_global_load_lds(
                (const __attribute__((address_space(1))) void*)(src + s_off[it] + dd),
                (__attribute__((address_space(3))) void*)(&Bs[buf][it * 2048 + ldsbase]),
                16, 0, 0);
    };

    stage_A(0, 0);
    stage_B(0, 0);
    int cur = 0;
    for (int kk = 0; kk < nchunks; kk++) {
        if (kk + 1 < nchunks) {
            // Issue next chunk's 6 loads FIRST, then wait for all but those 6:
            // chunk kk (issued a full iteration ago) is complete; kk+1 flies
            // across this chunk's MFMAs.
            stage_A(kk + 1, cur ^ 1);
            stage_B(kk + 1, cur ^ 1);
            asm volatile("s_waitcnt vmcnt(6)" ::: "memory");
        } else {
            asm volatile("s_waitcnt vmcnt(0)" ::: "memory");
        }
        __builtin_amdgcn_sched_barrier(0);
        asm volatile("s_barrier" ::: "memory");   // raw: no vmcnt(0) drain
#pragma unroll
        for (int k2 = 0; k2 < 2; k2++) {
            int sA = ((k2 * 4 + quad) ^ xa) * 8;
            bf16x8 af[4], bfr[2];
#pragma unroll
            for (int i = 0; i < 4; i++)
                af[i] = *(const bf16x8*)&As[cur][(wr * 64 + i * 16 + l15) * 64 + sA];
#pragma unroll
            for (int j = 0; j < 2; j++)
                bfr[j] = *(const bf16x8*)&Bs[cur][(wc * 32 + j * 16 + l15) * 64 + sA];
#pragma unroll
            for (int i = 0; i < 4; i++)
#pragma unroll
                for (int j = 0; j < 2; j++)
                    acc[i][j] = __builtin_amdgcn_mfma_f32_16x16x32_bf16(
                        af[i], bfr[j], acc[i][j], 0, 0, 0);
        }
        asm volatile("s_barrier" ::: "memory");   // protect As/Bs[cur] before overwrite
        cur ^= 1;
    }

    // ---- Epilogue ----------------------------------------------------------
    // Lane (quad,l15) of wave (wr,wc), tile (i,j): reg r = gate,
    // hid = oc'/4, px = col. Cell update in-register; h staged via LDS
    // (stride 40 to break bank conflicts) for coalesced NHWC stores.
    short* hl = &As[0][0];                // reuse: all LDS reads fenced above
    const int hid0 = oc0 >> 2;            // 0 or 32
#pragma unroll
    for (int i = 0; i < 4; i++) {
        int hidl = wr * 16 + i * 4 + quad;       // 0..31
        int hid = hid0 + hidl;
#pragma unroll
        for (int j = 0; j < 2; j++) {
            int pxl = wc * 32 + j * 16 + l15;    // 0..63
            int px = px0 + pxl;
            int b = px >> 12, p = px & 4095;
            size_t ci = ((size_t)(b * HID + hid)) * HW + p;
            float cv = first ? 0.0f : cbuf[ci];
            bf16x8 wv = *(const bf16x8*)&wcb[((size_t)hid * HW + p) * 8];
            float pg[4];
#pragma unroll
            for (int r = 0; r < 4; r++)
                pg[r] = acc[i][j][r] + bf2f(wv[r]) * cv + bf2f(wv[4 + r]);
            float ig = sigmoidf_(pg[0]);
            float fg = sigmoidf_(pg[1]);
            float gg = tanh_fast(pg[2]);
            float og = sigmoidf_(pg[3]);
            float cn = fg * cv + ig * gg;
            cbuf[ci] = cn;
            float hn = og * tanh_fast(cn);
            hl[pxl * 40 + hidl] = f2bf(hn);
        }
    }
    __syncthreads();
    {
        int task = tid;                          // 64 px x 4 q = 256 tasks
        int pxl = task >> 2, q = task & 3;
        bf16x8 v = *(const bf16x8*)&hl[pxl * 40 + q * 8];
        int px = px0 + pxl;
        int b = px >> 12, p = px & 4095, y = p >> 6, x = p & 63;
        *(bf16x8*)&hout[((size_t)((b * PADW + y + 1) * PADW + (x + 1))) * HID
                        + hid0 + q * 8] = v;
    }
}

// ---------------------------------------------------------------------------
// Final 1-out-channel 3x3 conv + sigmoid over packed bf16 h (padded NHWC).
// 256 blocks x 128 threads: covers all 256 CUs. Separate kernel: cannot
// perturb the gemm kernel's regalloc (round-4 lesson).
__global__ __launch_bounds__(128) void final_conv(
    const __hip_bfloat16* __restrict__ ph, const float* __restrict__ fw,
    const float* __restrict__ fb, float* __restrict__ out, int f) {
    int b = blockIdx.y;
    int p = blockIdx.x * 128 + threadIdx.x;
    int y = p >> 6, x = p & 63;
    float acc = fb[0];
#pragma unroll
    for (int tap = 0; tap < 9; tap++) {
        const bf16x8* base = (const bf16x8*)(
            ph + ((b * PADW + y + (tap / 3)) * PADW + (x + (tap % 3))) * HID);
#pragma unroll
        for (int c8 = 0; c8 < 8; c8++) {
            bf16x8 v = base[c8];
#pragma unroll
            for (int jj = 0; jj < 8; jj++)
                acc = fmaf(bf2f(v[jj]), fw[(c8 * 8 + jj) * 9 + tap], acc);
        }
    }
    out[((size_t)(b * FLEN + f)) * HW + p] = sigmoidf_(acc);
}

// ---------------------------------------------------------------------------
extern "C" void kernel_launch(void* const* d_in, const int* in_sizes, int n_in,
                              void* d_out, int out_size, void* d_ws, size_t ws_size,
                              hipStream_t stream) {
    const float* x = (const float*)d_in[0];
    const float* Wx_[4] = {(const float*)d_in[1], (const float*)d_in[5],
                           (const float*)d_in[9], (const float*)d_in[13]};
    const float* Wh_[4] = {(const float*)d_in[2], (const float*)d_in[6],
                           (const float*)d_in[10], (const float*)d_in[14]};
    const float* Wc_[4] = {(const float*)d_in[3], (const float*)d_in[7],
                           (const float*)d_in[11], (const float*)d_in[15]};
    const float* b_[4]  = {(const float*)d_in[4], (const float*)d_in[8],
                           (const float*)d_in[12], (const float*)d_in[16]};
    const float* fin_w  = (const float*)d_in[17];
    const float* fin_b  = (const float*)d_in[18];
    float* out = (float*)d_out;

    // Workspace layout:
    //   [8 h double-buffers bf16]  (memset to 0: initial states + halo rings)
    //   [10 px_all bf16]           (written by pack_x_all; poison elsewhere ok)
    //   [4 c states fp32]          (FIRST kernels don't read)
    //   [4 wcb bf16]  [4 Bw bf16]
    char* wsb = (char*)d_ws;
    const size_t H_BYTES  = 8ull * PADSZ * sizeof(short);       // 35,684,352
    const size_t PX_BYTES = 10ull * PADSZ * sizeof(short);      // 44,605,440
    const size_t C_BYTES  = 4ull * SB * sizeof(float);          // 33,554,432
    const size_t WCB_ELEM = (size_t)HID * HW * 8;               // per cell

    __hip_bfloat16* hb = (__hip_bfloat16*)wsb;
    __hip_bfloat16* px_all = (__hip_bfloat16*)(wsb + H_BYTES);
    float* cbuf = (float*)(wsb + H_BYTES + PX_BYTES);
    __hip_bfloat16* wcb = (__hip_bfloat16*)(wsb + H_BYTES + PX_BYTES + C_BYTES);
    __hip_bfloat16* bw = wcb + 4 * WCB_ELEM;

    __hip_bfloat16* e0buf[2] = {hb + 0 * (size_t)PADSZ, hb + 1 * (size_t)PADSZ};
    __hip_bfloat16* e1buf[2] = {hb + 2 * (size_t)PADSZ, hb + 3 * (size_t)PADSZ};
    __hip_bfloat16* d0buf[2] = {hb + 4 * (size_t)PADSZ, hb + 5 * (size_t)PADSZ};
    __hip_bfloat16* d1buf[2] = {hb + 6 * (size_t)PADSZ, hb + 7 * (size_t)PADSZ};

    float* ec0 = cbuf + 0 * (size_t)SB;
    float* ec1 = cbuf + 1 * (size_t)SB;
    float* dc0 = cbuf + 2 * (size_t)SB;
    float* dc1 = cbuf + 3 * (size_t)SB;

    __hip_bfloat16* wcb_[4] = {wcb, wcb + WCB_ELEM, wcb + 2 * WCB_ELEM, wcb + 3 * WCB_ELEM};
    __hip_bfloat16* bw_e0 = bw;
    __hip_bfloat16* bw_e1 = bw_e0 + (size_t)OC4 * KT_E0;
    __hip_bfloat16* bw_d0 = bw_e1 + (size_t)OC4 * KT_STD;
    __hip_bfloat16* bw_d1 = bw_d0 + (size_t)OC4 * KT_STD;
    __hip_bfloat16* bw_[4] = {bw_e0, bw_e1, bw_d0, bw_d1};
    float* c_[4] = {ec0, ec1, dc0, dc1};

    hipMemsetAsync(wsb, 0, H_BYTES, stream);

    reorder_w<<<dim3(OC4), 256, 0, stream>>>(Wx_[0], 1,   Wh_[0], bw_e0, KT_E0);
    reorder_w<<<dim3(OC4), 256, 0, stream>>>(Wx_[1], HID, Wh_[1], bw_e1, KT_STD);
    reorder_w<<<dim3(OC4), 256, 0, stream>>>(Wx_[2], HID, Wh_[2], bw_d0, KT_STD);
    reorder_w<<<dim3(OC4), 256, 0, stream>>>(Wx_[3], HID, Wh_[3], bw_d1, KT_STD);
    for (int cix = 0; cix < 4; cix++)
        pack_wcb<<<dim3((HID * HW) / 256), 256, 0, stream>>>(Wc_[cix], b_[cix], wcb_[cix]);
    pack_x_all<<<dim3((TSTEPS * BSZ * PPIX + 255) / 256), 256, 0, stream>>>(x, px_all);

    auto cellargs = [&](int cell, const __hip_bfloat16* s0, const __hip_bfloat16* s1,
                        __hip_bfloat16* ho, int kt, int nn0, int fi) {
        CellArgs a;
        a.Bw = bw_[cell]; a.src0 = s0; a.src1 = s1; a.wcb = wcb_[cell];
        a.cbuf = c_[cell]; a.hout = ho; a.ktot = kt; a.n0 = nn0; a.first = fi;
        return a;
    };
    auto px = [&](int t) { return px_all + (size_t)t * PADSZ; };

    dim3 gfin(32, BSZ);

    // --- Encoder, software-pipelined: dispatch k runs enc0(t=k) || enc1(t=k-1).
    // e0h(t) lives in e0buf[t&1]; e1h(t) in e1buf[t&1]; t=-1 state = zeros in buf[1].
    {
        CellArgs a = cellargs(0, px(0), e0buf[1], e0buf[0], KT_E0, 1, 1);
        gemm_cell_fused<<<dim3(512, 2, 1), 256, 0, stream>>>(a, a);
    }
    for (int k = 1; k <= 9; k++) {
        int t0 = k, t1 = k - 1;
        CellArgs a0 = cellargs(0, px(t0), e0buf[(t0 - 1) & 1], e0buf[t0 & 1],
                               KT_E0, 1, 0);
        CellArgs a1 = cellargs(1, e0buf[t1 & 1], e1buf[(t1 - 1) & 1], e1buf[t1 & 1],
                               KT_STD, 9, (t1 == 0) ? 1 : 0);
        gemm_cell_fused<<<dim3(512, 2, 2), 256, 0, stream>>>(a0, a1);
    }
    {
        CellArgs a = cellargs(1, e0buf[1], e1buf[0], e1buf[1], KT_STD, 9, 0); // t=9
        gemm_cell_fused<<<dim3(512, 2, 1), 256, 0, stream>>>(a, a);
    }
    __hip_bfloat16* enc_top = e1buf[1];   // e1h(9)

    // --- Decoder (strictly sequential chain)
    for (int f = 0; f < FLEN; f++) {
        const __hip_bfloat16* s = (f == 0) ? enc_top : d1buf[(f - 1) & 1];
        CellArgs a0 = cellargs(2, s, d0buf[(f - 1) & 1], d0buf[f & 1],
                               KT_STD, 9, (f == 0) ? 1 : 0);
        gemm_cell_fused<<<dim3(512, 2, 1), 256, 0, stream>>>(a0, a0);
        CellArgs a1 = cellargs(3, d0buf[f & 1], d1buf[(f - 1) & 1], d1buf[f & 1],
                               KT_STD, 9, (f == 0) ? 1 : 0);
        gemm_cell_fused<<<dim3(512, 2, 1), 256, 0, stream>>>(a1, a1);
        final_conv<<<gfin, 128, 0, stream>>>(d1buf[f & 1], fin_w, fin_b, out, f);
    }
}

// Round 12
// 1421.861 us; speedup vs baseline: 1.1640x; 1.1640x over previous
//
#include <hip/hip_runtime.h>
#include <hip/hip_bf16.h>
#include <math.h>

// Problem constants (fixed by setup_inputs)
#define BSZ    8
#define TSTEPS 10
#define FLEN   10
#define HID    64
#define HW     4096                 // 64*64
#define IMG    (HID * HW)           // 262144
#define OC4    (4 * HID)            // 256 gate channels
#define PADW   66
#define PPIX   (PADW * PADW)        // 4356
#define PADIMG (PPIX * HID)         // padded NHWC plane per batch
#define PADSZ  (BSZ * PADIMG)       // 2230272 bf16 elems per buffer
#define SB     (BSZ * IMG)          // 2097152 floats (one c state)
#define KT_E0  640                  // enc0: 1 x-im2col chunk + 9 h chunks
#define KT_STD 1152                 // 9 x chunks + 9 h chunks

typedef __attribute__((ext_vector_type(8))) short bf16x8;
typedef __attribute__((ext_vector_type(4))) float f32x4;

__device__ __forceinline__ float sigmoidf_(float x) {
    return 1.0f / (1.0f + __expf(-x));
}
__device__ __forceinline__ float tanh_fast(float x) {
    float e = __expf(2.0f * x);
    return 1.0f - 2.0f / (e + 1.0f);     // exact at +-inf saturation
}
__device__ __forceinline__ float bf2f(short u) {
    union { unsigned u; float f; } cv;
    cv.u = ((unsigned)(unsigned short)u) << 16;
    return cv.f;
}
__device__ __forceinline__ short f2bf(float x) {
    __hip_bfloat16 h = __float2bfloat16(x);
    union { __hip_bfloat16 h; short s; } cv; cv.h = h;
    return cv.s;
}

// ---------------------------------------------------------------------------
// Weight reorder -> Bw[oc'=hid*4+gate][k], bf16. Source oc = gate*64+hid.
// icx==1 (enc0): chunk0 = x-im2col taps (9 live of 64), chunks 1..9 = Wh taps.
// else: chunks 0..8 = Wx taps, 9..17 = Wh taps (64 ch each).
__global__ __launch_bounds__(256) void reorder_w(
    const float* __restrict__ Wx, int icx,
    const float* __restrict__ Wh, __hip_bfloat16* __restrict__ Bw, int ktot) {
    int ocp = blockIdx.x, hid = ocp >> 2, gate = ocp & 3;
    int oc = gate * 64 + hid;
    for (int k = threadIdx.x; k < ktot; k += 256) {
        int c = k >> 6, j = k & 63;
        float v;
        if (icx == 1) {
            if (c == 0) v = (j < 9) ? Wx[oc * 9 + j] : 0.0f;
            else        v = Wh[(oc * 64 + j) * 9 + (c - 1)];
        } else {
            if (c < 9)  v = Wx[(oc * 64 + j) * 9 + c];
            else        v = Wh[(oc * 64 + j) * 9 + (c - 9)];
        }
        Bw[ocp * ktot + k] = __float2bfloat16(v);
    }
}

// ---------------------------------------------------------------------------
// Pack Wc + bias -> wcb[hid*HW + p][8] bf16: [Wc g0..g3, bias g0..g3].
__global__ __launch_bounds__(256) void pack_wcb(
    const float* __restrict__ Wc, const float* __restrict__ bias,
    __hip_bfloat16* __restrict__ wcb) {
    int i = blockIdx.x * 256 + threadIdx.x;   // 0 .. HID*HW-1
    int hid = i >> 12, p = i & 4095;
    union { short s[8]; bf16x8 v; } u;
#pragma unroll
    for (int g = 0; g < 4; g++) {
        u.s[g]     = f2bf(Wc[(g * HID + hid) * HW + p]);
        u.s[4 + g] = f2bf(bias[(g * HID + hid) * HW + p]);
    }
    *(bf16x8*)&wcb[(size_t)i * 8] = u.v;
}

// ---------------------------------------------------------------------------
// im2col of x for ALL timesteps into padded NHWC bf16: ch 0..8 = 3x3 taps,
// ch 9..15 zero; ch 16..63 left as poison (only multiplied by zero weights).
// Covers the full 66x66 padded grid (ring written as zeros; never read anyway).
__global__ __launch_bounds__(256) void pack_x_all(
    const float* __restrict__ x, __hip_bfloat16* __restrict__ px_all) {
    int i = blockIdx.x * 256 + threadIdx.x;   // 0 .. 10*8*4356-1
    if (i >= TSTEPS * BSZ * PPIX) return;
    int t = i / (BSZ * PPIX);
    int rem = i - t * (BSZ * PPIX);
    int b = rem / PPIX;
    int pp = rem - b * PPIX;
    int y = pp / PADW, xx = pp - y * PADW;    // padded coords 0..65
    int oy = y - 1, ox = xx - 1;
    const float* xb = x + ((size_t)(b * TSTEPS + t)) * HW;
    bool interior = (oy >= 0 && oy < 64 && ox >= 0 && ox < 64);
    union { short s[16]; bf16x8 v[2]; } u;
#pragma unroll
    for (int tap = 0; tap < 9; tap++) {
        int yy = oy + tap / 3 - 1, xc = ox + tap % 3 - 1;
        float val = (interior && yy >= 0 && yy < 64 && xc >= 0 && xc < 64)
                        ? xb[yy * 64 + xc] : 0.0f;
        u.s[tap] = f2bf(val);
    }
#pragma unroll
    for (int tap = 9; tap < 16; tap++) u.s[tap] = 0;
    short* o = (short*)(px_all + (size_t)t * PADSZ + ((size_t)(b * PPIX + pp)) * HID);
    *(bf16x8*)&o[0] = u.v[0];
    *(bf16x8*)&o[8] = u.v[1];
}

// ---------------------------------------------------------------------------
struct CellArgs {
    const __hip_bfloat16* Bw;
    const __hip_bfloat16* src0;
    const __hip_bfloat16* src1;
    const __hip_bfloat16* wcb;
    float* cbuf;
    __hip_bfloat16* hout;
    int ktot;   // 640 or 1152
    int n0;     // 1 or 9
    int first;  // skip c read (h(-1)=c(-1)=0)
};

// Fused im2col-GEMM + LSTM cell. M=256 (oc'=hid*4+gate), N=32768 (px), K=ktot.
// 128oc x 64px tile, 4 waves (wave = 64oc x 32px, acc[4][2]).
// FINAL configuration (session best, 1389 us measured at round 10):
// Bs (the HBM-side src load) double-buffered with counted vmcnt(2); raw
// s_barrier (memory clobber) so the prefetch is not drained. Hazards: each
// wave waits its own A(kk)/B(kk) via vmcnt(2) before barrier1; As overwrite
// happens after barrier2 = after all reads; Bs[nxt] was last read in chunk
// kk-1, fenced by its barrier2.
// Session ladder (r0-r11): wins were occupancy hygiene (VGPR<=64, ~4
// blocks/CU, no regalloc-poisoning branch in this kernel) and full-CU
// final_conv. Refuted levers: 8-wave blocks (r3), >4 blocks/CU via smaller
// tiles (r7: L2-traffic trade), halo restructure with A in VGPR (r8/r9:
// per-chunk latency chain), full A+B dbuf with vmcnt(6) (r11: VGPR 68 +
// 48KB LDS -> 3 blocks/CU + L2-locality loss, 1655us).
// blockIdx.z selects one of two independent cell-steps (encoder pipelining).
// Epilogue: in-register cell update; h transposed through LDS -> coalesced
// 16B NHWC stores.
__global__ __launch_bounds__(256, 4) void gemm_cell_fused(CellArgs A0, CellArgs A1) {
    __shared__ short As[128 * 64];      // 16 KB, single-buffered (L2-resident src)
    __shared__ short Bs[2][64 * 64];    // 2 x 8 KB, double-buffered (HBM-side src)

    const bool z1 = (blockIdx.z != 0);
    const __hip_bfloat16* __restrict__ Bw   = z1 ? A1.Bw   : A0.Bw;
    const __hip_bfloat16* __restrict__ src0 = z1 ? A1.src0 : A0.src0;
    const __hip_bfloat16* __restrict__ src1 = z1 ? A1.src1 : A0.src1;
    const __hip_bfloat16* __restrict__ wcb  = z1 ? A1.wcb  : A0.wcb;
    float* __restrict__ cbuf                = z1 ? A1.cbuf : A0.cbuf;
    __hip_bfloat16* __restrict__ hout       = z1 ? A1.hout : A0.hout;
    const int ktot  = z1 ? A1.ktot  : A0.ktot;
    const int n0    = z1 ? A1.n0    : A0.n0;
    const int first = z1 ? A1.first : A0.first;

    const int tid  = threadIdx.x;
    const int lane = tid & 63;
    const int wave = tid >> 6;       // 0..3
    const int quad = lane >> 4;
    const int l15  = lane & 15;
    const int wr = wave >> 1;        // 0..1  (64-row oc' half)
    const int wc = wave & 1;         // 0..1  (32-col px half)
    const int px0 = blockIdx.x * 64;
    const int oc0 = blockIdx.y * 128;

    // A staging: 128 rows x 8 segs = 1024 tasks -> 4 rounds of 256.
    // B staging: 64 rows x 8 segs = 512 tasks -> 2 rounds of 256.
    int a_off[4], s_off[2];
#pragma unroll
    for (int it = 0; it < 4; it++) {
        int idx = it * 256 + tid;
        int rr = idx >> 3, seg = idx & 7;
        int segx = seg ^ (rr & 7);            // global-side swizzle
        a_off[it] = (oc0 + rr) * ktot + segx * 8;
    }
#pragma unroll
    for (int it = 0; it < 2; it++) {
        int idx = it * 256 + tid;
        int rr = idx >> 3, seg = idx & 7;
        int segx = seg ^ (rr & 7);
        int px = px0 + rr;
        int b = px >> 12, p = px & 4095, y = p >> 6, x = p & 63;
        s_off[it] = ((b * PADW + y + 1) * PADW + (x + 1)) * HID + segx * 8;
    }
    const int ldsbase = (tid & ~63) * 8;      // wave-uniform
    const int xa = l15 & 7;                   // read-side swizzle (= row&7)

    f32x4 acc[4][2] = {};
    const int nchunks = n0 + 9;

    auto stage_A = [&](int kk) {
        int ka = kk * 64;
#pragma unroll
        for (int it = 0; it < 4; it++)
            __builtin_amdgcn_global_load_lds(
                (const __attribute__((address_space(1))) void*)(Bw + a_off[it] + ka),
                (__attribute__((address_space(3))) void*)(&As[it * 2048 + ldsbase]),
                16, 0, 0);
    };
    auto stage_B = [&](int kk, int buf) {
        const __hip_bfloat16* src;
        int tap;
        if (kk < n0) { src = src0; tap = (n0 == 1) ? 4 : kk; }
        else         { src = src1; tap = kk - n0; }
        int dd = ((tap / 3) - 1) * (PADW * HID) + ((tap % 3) - 1) * HID;
#pragma unroll
        for (int it = 0; it < 2; it++)
            __builtin_amdgcn_global_load_lds(
                (const __attribute__((address_space(1))) void*)(src + s_off[it] + dd),
                (__attribute__((address_space(3))) void*)(&Bs[buf][it * 2048 + ldsbase]),
                16, 0, 0);
    };

    stage_B(0, 0);
    int cur = 0;
    for (int kk = 0; kk < nchunks; kk++) {
        stage_A(kk);                          // As free: all reads fenced by prev barrier2
        if (kk + 1 < nchunks) {
            stage_B(kk + 1, cur ^ 1);         // prefetch next h-tile
            // Wait for all but the 2 newest (the prefetch): A(kk)+B(kk) done.
            asm volatile("s_waitcnt vmcnt(2)" ::: "memory");
        } else {
            asm volatile("s_waitcnt vmcnt(0)" ::: "memory");
        }
        __builtin_amdgcn_sched_barrier(0);
        asm volatile("s_barrier" ::: "memory");   // raw: no vmcnt(0) drain
#pragma unroll
        for (int k2 = 0; k2 < 2; k2++) {
            int sA = ((k2 * 4 + quad) ^ xa) * 8;
            bf16x8 af[4], bfr[2];
#pragma unroll
            for (int i = 0; i < 4; i++)
                af[i] = *(const bf16x8*)&As[(wr * 64 + i * 16 + l15) * 64 + sA];
#pragma unroll
            for (int j = 0; j < 2; j++)
                bfr[j] = *(const bf16x8*)&Bs[cur][(wc * 32 + j * 16 + l15) * 64 + sA];
#pragma unroll
            for (int i = 0; i < 4; i++)
#pragma unroll
                for (int j = 0; j < 2; j++)
                    acc[i][j] = __builtin_amdgcn_mfma_f32_16x16x32_bf16(
                        af[i], bfr[j], acc[i][j], 0, 0, 0);
        }
        asm volatile("s_barrier" ::: "memory");   // protect As/Bs[cur] before overwrite
        cur ^= 1;
    }

    // ---- Epilogue ----------------------------------------------------------
    // Lane (quad,l15) of wave (wr,wc), tile (i,j): reg r = gate,
    // hid = oc'/4, px = col. Cell update in-register; h staged via LDS
    // (stride 40 to break bank conflicts) for coalesced NHWC stores.
    short* hl = As;                       // reuse: all LDS reads fenced above
    const int hid0 = oc0 >> 2;            // 0 or 32
#pragma unroll
    for (int i = 0; i < 4; i++) {
        int hidl = wr * 16 + i * 4 + quad;       // 0..31
        int hid = hid0 + hidl;
#pragma unroll
        for (int j = 0; j < 2; j++) {
            int pxl = wc * 32 + j * 16 + l15;    // 0..63
            int px = px0 + pxl;
            int b = px >> 12, p = px & 4095;
            size_t ci = ((size_t)(b * HID + hid)) * HW + p;
            float cv = first ? 0.0f : cbuf[ci];
            bf16x8 wv = *(const bf16x8*)&wcb[((size_t)hid * HW + p) * 8];
            float pg[4];
#pragma unroll
            for (int r = 0; r < 4; r++)
                pg[r] = acc[i][j][r] + bf2f(wv[r]) * cv + bf2f(wv[4 + r]);
            float ig = sigmoidf_(pg[0]);
            float fg = sigmoidf_(pg[1]);
            float gg = tanh_fast(pg[2]);
            float og = sigmoidf_(pg[3]);
            float cn = fg * cv + ig * gg;
            cbuf[ci] = cn;
            float hn = og * tanh_fast(cn);
            hl[pxl * 40 + hidl] = f2bf(hn);
        }
    }
    __syncthreads();
    {
        int task = tid;                          // 64 px x 4 q = 256 tasks
        int pxl = task >> 2, q = task & 3;
        bf16x8 v = *(const bf16x8*)&hl[pxl * 40 + q * 8];
        int px = px0 + pxl;
        int b = px >> 12, p = px & 4095, y = p >> 6, x = p & 63;
        *(bf16x8*)&hout[((size_t)((b * PADW + y + 1) * PADW + (x + 1))) * HID
                        + hid0 + q * 8] = v;
    }
}

// ---------------------------------------------------------------------------
// Final 1-out-channel 3x3 conv + sigmoid over packed bf16 h (padded NHWC).
// 256 blocks x 128 threads: covers all 256 CUs. Separate kernel: cannot
// perturb the gemm kernel's regalloc (round-4 lesson).
__global__ __launch_bounds__(128) void final_conv(
    const __hip_bfloat16* __restrict__ ph, const float* __restrict__ fw,
    const float* __restrict__ fb, float* __restrict__ out, int f) {
    int b = blockIdx.y;
    int p = blockIdx.x * 128 + threadIdx.x;
    int y = p >> 6, x = p & 63;
    float acc = fb[0];
#pragma unroll
    for (int tap = 0; tap < 9; tap++) {
        const bf16x8* base = (const bf16x8*)(
            ph + ((b * PADW + y + (tap / 3)) * PADW + (x + (tap % 3))) * HID);
#pragma unroll
        for (int c8 = 0; c8 < 8; c8++) {
            bf16x8 v = base[c8];
#pragma unroll
            for (int jj = 0; jj < 8; jj++)
                acc = fmaf(bf2f(v[jj]), fw[(c8 * 8 + jj) * 9 + tap], acc);
        }
    }
    out[((size_t)(b * FLEN + f)) * HW + p] = sigmoidf_(acc);
}

// ---------------------------------------------------------------------------
extern "C" void kernel_launch(void* const* d_in, const int* in_sizes, int n_in,
                              void* d_out, int out_size, void* d_ws, size_t ws_size,
                              hipStream_t stream) {
    const float* x = (const float*)d_in[0];
    const float* Wx_[4] = {(const float*)d_in[1], (const float*)d_in[5],
                           (const float*)d_in[9], (const float*)d_in[13]};
    const float* Wh_[4] = {(const float*)d_in[2], (const float*)d_in[6],
                           (const float*)d_in[10], (const float*)d_in[14]};
    const float* Wc_[4] = {(const float*)d_in[3], (const float*)d_in[7],
                           (const float*)d_in[11], (const float*)d_in[15]};
    const float* b_[4]  = {(const float*)d_in[4], (const float*)d_in[8],
                           (const float*)d_in[12], (const float*)d_in[16]};
    const float* fin_w  = (const float*)d_in[17];
    const float* fin_b  = (const float*)d_in[18];
    float* out = (float*)d_out;

    // Workspace layout:
    //   [8 h double-buffers bf16]  (memset to 0: initial states + halo rings)
    //   [10 px_all bf16]           (written by pack_x_all; poison elsewhere ok)
    //   [4 c states fp32]          (FIRST kernels don't read)
    //   [4 wcb bf16]  [4 Bw bf16]
    char* wsb = (char*)d_ws;
    const size_t H_BYTES  = 8ull * PADSZ * sizeof(short);       // 35,684,352
    const size_t PX_BYTES = 10ull * PADSZ * sizeof(short);      // 44,605,440
    const size_t C_BYTES  = 4ull * SB * sizeof(float);          // 33,554,432
    const size_t WCB_ELEM = (size_t)HID * HW * 8;               // per cell

    __hip_bfloat16* hb = (__hip_bfloat16*)wsb;
    __hip_bfloat16* px_all = (__hip_bfloat16*)(wsb + H_BYTES);
    float* cbuf = (float*)(wsb + H_BYTES + PX_BYTES);
    __hip_bfloat16* wcb = (__hip_bfloat16*)(wsb + H_BYTES + PX_BYTES + C_BYTES);
    __hip_bfloat16* bw = wcb + 4 * WCB_ELEM;

    __hip_bfloat16* e0buf[2] = {hb + 0 * (size_t)PADSZ, hb + 1 * (size_t)PADSZ};
    __hip_bfloat16* e1buf[2] = {hb + 2 * (size_t)PADSZ, hb + 3 * (size_t)PADSZ};
    __hip_bfloat16* d0buf[2] = {hb + 4 * (size_t)PADSZ, hb + 5 * (size_t)PADSZ};
    __hip_bfloat16* d1buf[2] = {hb + 6 * (size_t)PADSZ, hb + 7 * (size_t)PADSZ};

    float* ec0 = cbuf + 0 * (size_t)SB;
    float* ec1 = cbuf + 1 * (size_t)SB;
    float* dc0 = cbuf + 2 * (size_t)SB;
    float* dc1 = cbuf + 3 * (size_t)SB;

    __hip_bfloat16* wcb_[4] = {wcb, wcb + WCB_ELEM, wcb + 2 * WCB_ELEM, wcb + 3 * WCB_ELEM};
    __hip_bfloat16* bw_e0 = bw;
    __hip_bfloat16* bw_e1 = bw_e0 + (size_t)OC4 * KT_E0;
    __hip_bfloat16* bw_d0 = bw_e1 + (size_t)OC4 * KT_STD;
    __hip_bfloat16* bw_d1 = bw_d0 + (size_t)OC4 * KT_STD;
    __hip_bfloat16* bw_[4] = {bw_e0, bw_e1, bw_d0, bw_d1};
    float* c_[4] = {ec0, ec1, dc0, dc1};

    hipMemsetAsync(wsb, 0, H_BYTES, stream);

    reorder_w<<<dim3(OC4), 256, 0, stream>>>(Wx_[0], 1,   Wh_[0], bw_e0, KT_E0);
    reorder_w<<<dim3(OC4), 256, 0, stream>>>(Wx_[1], HID, Wh_[1], bw_e1, KT_STD);
    reorder_w<<<dim3(OC4), 256, 0, stream>>>(Wx_[2], HID, Wh_[2], bw_d0, KT_STD);
    reorder_w<<<dim3(OC4), 256, 0, stream>>>(Wx_[3], HID, Wh_[3], bw_d1, KT_STD);
    for (int cix = 0; cix < 4; cix++)
        pack_wcb<<<dim3((HID * HW) / 256), 256, 0, stream>>>(Wc_[cix], b_[cix], wcb_[cix]);
    pack_x_all<<<dim3((TSTEPS * BSZ * PPIX + 255) / 256), 256, 0, stream>>>(x, px_all);

    auto cellargs = [&](int cell, const __hip_bfloat16* s0, const __hip_bfloat16* s1,
                        __hip_bfloat16* ho, int kt, int nn0, int fi) {
        CellArgs a;
        a.Bw = bw_[cell]; a.src0 = s0; a.src1 = s1; a.wcb = wcb_[cell];
        a.cbuf = c_[cell]; a.hout = ho; a.ktot = kt; a.n0 = nn0; a.first = fi;
        return a;
    };
    auto px = [&](int t) { return px_all + (size_t)t * PADSZ; };

    dim3 gfin(32, BSZ);

    // --- Encoder, software-pipelined: dispatch k runs enc0(t=k) || enc1(t=k-1).
    // e0h(t) lives in e0buf[t&1]; e1h(t) in e1buf[t&1]; t=-1 state = zeros in buf[1].
    {
        CellArgs a = cellargs(0, px(0), e0buf[1], e0buf[0], KT_E0, 1, 1);
        gemm_cell_fused<<<dim3(512, 2, 1), 256, 0, stream>>>(a, a);
    }
    for (int k = 1; k <= 9; k++) {
        int t0 = k, t1 = k - 1;
        CellArgs a0 = cellargs(0, px(t0), e0buf[(t0 - 1) & 1], e0buf[t0 & 1],
                               KT_E0, 1, 0);
        CellArgs a1 = cellargs(1, e0buf[t1 & 1], e1buf[(t1 - 1) & 1], e1buf[t1 & 1],
                               KT_STD, 9, (t1 == 0) ? 1 : 0);
        gemm_cell_fused<<<dim3(512, 2, 2), 256, 0, stream>>>(a0, a1);
    }
    {
        CellArgs a = cellargs(1, e0buf[1], e1buf[0], e1buf[1], KT_STD, 9, 0); // t=9
        gemm_cell_fused<<<dim3(512, 2, 1), 256, 0, stream>>>(a, a);
    }
    __hip_bfloat16* enc_top = e1buf[1];   // e1h(9)

    // --- Decoder (strictly sequential chain)
    for (int f = 0; f < FLEN; f++) {
        const __hip_bfloat16* s = (f == 0) ? enc_top : d1buf[(f - 1) & 1];
        CellArgs a0 = cellargs(2, s, d0buf[(f - 1) & 1], d0buf[f & 1],
                               KT_STD, 9, (f == 0) ? 1 : 0);
        gemm_cell_fused<<<dim3(512, 2, 1), 256, 0, stream>>>(a0, a0);
        CellArgs a1 = cellargs(3, d0buf[f & 1], d1buf[(f - 1) & 1], d1buf[f & 1],
                               KT_STD, 9, (f == 0) ? 1 : 0);
        gemm_cell_fused<<<dim3(512, 2, 1), 256, 0, stream>>>(a1, a1);
        final_conv<<<gfin, 128, 0, stream>>>(d1buf[f & 1], fin_w, fin_b, out, f);
    }
}

// Round 13
// 1373.791 us; speedup vs baseline: 1.2048x; 1.0350x over previous
//
#include <hip/hip_runtime.h>
#include <hip/hip_bf16.h>
#include <math.h>

// Problem constants (fixed by setup_inputs)
#define BSZ    8
#define TSTEPS 10
#define FLEN   10
#define HID    64
#define HW     4096                 // 64*64
#define IMG    (HID * HW)           // 262144
#define OC4    (4 * HID)            // 256 gate channels
#define PADW   66
#define PPIX   (PADW * PADW)        // 4356
#define PADIMG (PPIX * HID)         // padded NHWC plane per batch
#define PADSZ  (BSZ * PADIMG)       // 2230272 bf16 elems per buffer
#define SB     (BSZ * IMG)          // 2097152 floats (one c state)
#define KT_E0  640                  // enc0: 1 x-im2col chunk + 9 h chunks
#define KT_STD 1152                 // 9 x chunks + 9 h chunks

typedef __attribute__((ext_vector_type(8))) short bf16x8;
typedef __attribute__((ext_vector_type(4))) float f32x4;

__device__ __forceinline__ float sigmoidf_(float x) {
    return 1.0f / (1.0f + __expf(-x));
}
__device__ __forceinline__ float tanh_fast(float x) {
    float e = __expf(2.0f * x);
    return 1.0f - 2.0f / (e + 1.0f);     // exact at +-inf saturation
}
__device__ __forceinline__ float bf2f(short u) {
    union { unsigned u; float f; } cv;
    cv.u = ((unsigned)(unsigned short)u) << 16;
    return cv.f;
}
__device__ __forceinline__ short f2bf(float x) {
    __hip_bfloat16 h = __float2bfloat16(x);
    union { __hip_bfloat16 h; short s; } cv; cv.h = h;
    return cv.s;
}

// ---------------------------------------------------------------------------
// Weight reorder -> Bw[oc'=hid*4+gate][k], bf16. Source oc = gate*64+hid.
// icx==1 (enc0): chunk0 = x-im2col taps (9 live of 64), chunks 1..9 = Wh taps.
// else: chunks 0..8 = Wx taps, 9..17 = Wh taps (64 ch each).
__global__ __launch_bounds__(256) void reorder_w(
    const float* __restrict__ Wx, int icx,
    const float* __restrict__ Wh, __hip_bfloat16* __restrict__ Bw, int ktot) {
    int ocp = blockIdx.x, hid = ocp >> 2, gate = ocp & 3;
    int oc = gate * 64 + hid;
    for (int k = threadIdx.x; k < ktot; k += 256) {
        int c = k >> 6, j = k & 63;
        float v;
        if (icx == 1) {
            if (c == 0) v = (j < 9) ? Wx[oc * 9 + j] : 0.0f;
            else        v = Wh[(oc * 64 + j) * 9 + (c - 1)];
        } else {
            if (c < 9)  v = Wx[(oc * 64 + j) * 9 + c];
            else        v = Wh[(oc * 64 + j) * 9 + (c - 9)];
        }
        Bw[ocp * ktot + k] = __float2bfloat16(v);
    }
}

// ---------------------------------------------------------------------------
// Pack Wc + bias -> wcb[hid*HW + p][8] bf16: [Wc g0..g3, bias g0..g3].
__global__ __launch_bounds__(256) void pack_wcb(
    const float* __restrict__ Wc, const float* __restrict__ bias,
    __hip_bfloat16* __restrict__ wcb) {
    int i = blockIdx.x * 256 + threadIdx.x;   // 0 .. HID*HW-1
    int hid = i >> 12, p = i & 4095;
    union { short s[8]; bf16x8 v; } u;
#pragma unroll
    for (int g = 0; g < 4; g++) {
        u.s[g]     = f2bf(Wc[(g * HID + hid) * HW + p]);
        u.s[4 + g] = f2bf(bias[(g * HID + hid) * HW + p]);
    }
    *(bf16x8*)&wcb[(size_t)i * 8] = u.v;
}

// ---------------------------------------------------------------------------
// im2col of x for ALL timesteps into padded NHWC bf16: ch 0..8 = 3x3 taps,
// ch 9..15 zero; ch 16..63 left as poison (only multiplied by zero weights).
// Covers the full 66x66 padded grid (ring written as zeros; never read anyway).
__global__ __launch_bounds__(256) void pack_x_all(
    const float* __restrict__ x, __hip_bfloat16* __restrict__ px_all) {
    int i = blockIdx.x * 256 + threadIdx.x;   // 0 .. 10*8*4356-1
    if (i >= TSTEPS * BSZ * PPIX) return;
    int t = i / (BSZ * PPIX);
    int rem = i - t * (BSZ * PPIX);
    int b = rem / PPIX;
    int pp = rem - b * PPIX;
    int y = pp / PADW, xx = pp - y * PADW;    // padded coords 0..65
    int oy = y - 1, ox = xx - 1;
    const float* xb = x + ((size_t)(b * TSTEPS + t)) * HW;
    bool interior = (oy >= 0 && oy < 64 && ox >= 0 && ox < 64);
    union { short s[16]; bf16x8 v[2]; } u;
#pragma unroll
    for (int tap = 0; tap < 9; tap++) {
        int yy = oy + tap / 3 - 1, xc = ox + tap % 3 - 1;
        float val = (interior && yy >= 0 && yy < 64 && xc >= 0 && xc < 64)
                        ? xb[yy * 64 + xc] : 0.0f;
        u.s[tap] = f2bf(val);
    }
#pragma unroll
    for (int tap = 9; tap < 16; tap++) u.s[tap] = 0;
    short* o = (short*)(px_all + (size_t)t * PADSZ + ((size_t)(b * PPIX + pp)) * HID);
    *(bf16x8*)&o[0] = u.v[0];
    *(bf16x8*)&o[8] = u.v[1];
}

// ---------------------------------------------------------------------------
struct CellArgs {
    const __hip_bfloat16* Bw;
    const __hip_bfloat16* src0;
    const __hip_bfloat16* src1;
    const __hip_bfloat16* wcb;
    float* cbuf;
    __hip_bfloat16* hout;
    int ktot;   // 640 or 1152
    int n0;     // 1 or 9
    int first;  // skip c read (h(-1)=c(-1)=0)
};

// Fused im2col-GEMM + LSTM cell. M=256 (oc'=hid*4+gate), N=32768 (px), K=ktot.
// 128oc x 64px tile, 4 waves (wave = 64oc x 32px, acc[4][2]).
// FINAL configuration (session best, 1389 us @ r10, reproduced 1422 @ r12):
// Bs (the HBM-side src load) double-buffered with counted vmcnt(2); raw
// s_barrier (memory clobber) so the prefetch is not drained. Hazards: each
// wave waits its own A(kk)/B(kk) via vmcnt(2) before barrier1; As overwrite
// happens after barrier2 = after all reads; Bs[nxt] was last read in chunk
// kk-1, fenced by its barrier2.
// Session ladder (r0-r12): wins were occupancy hygiene (VGPR<=64, ~4
// blocks/CU, no regalloc-poisoning branch in this kernel) and full-CU
// final_conv. Refuted levers: 8-wave blocks (r3), >4 blocks/CU via smaller
// tiles (r7: L2-traffic trade), halo restructure with A in VGPR (r8/r9:
// per-chunk latency chain), full A+B dbuf with vmcnt(6) (r11: VGPR 68 +
// 48KB LDS -> 3 blocks/CU + L2-locality loss). Remaining 2x gap to the
// 26us/dual L2-staging floor is the 2-phase structural stall; every
// single-variable path to it measured worse.
// blockIdx.z selects one of two independent cell-steps (encoder pipelining).
// Epilogue: in-register cell update; h transposed through LDS -> coalesced
// 16B NHWC stores.
__global__ __launch_bounds__(256, 4) void gemm_cell_fused(CellArgs A0, CellArgs A1) {
    __shared__ short As[128 * 64];      // 16 KB, single-buffered (L2-resident src)
    __shared__ short Bs[2][64 * 64];    // 2 x 8 KB, double-buffered (HBM-side src)

    const bool z1 = (blockIdx.z != 0);
    const __hip_bfloat16* __restrict__ Bw   = z1 ? A1.Bw   : A0.Bw;
    const __hip_bfloat16* __restrict__ src0 = z1 ? A1.src0 : A0.src0;
    const __hip_bfloat16* __restrict__ src1 = z1 ? A1.src1 : A0.src1;
    const __hip_bfloat16* __restrict__ wcb  = z1 ? A1.wcb  : A0.wcb;
    float* __restrict__ cbuf                = z1 ? A1.cbuf : A0.cbuf;
    __hip_bfloat16* __restrict__ hout       = z1 ? A1.hout : A0.hout;
    const int ktot  = z1 ? A1.ktot  : A0.ktot;
    const int n0    = z1 ? A1.n0    : A0.n0;
    const int first = z1 ? A1.first : A0.first;

    const int tid  = threadIdx.x;
    const int lane = tid & 63;
    const int wave = tid >> 6;       // 0..3
    const int quad = lane >> 4;
    const int l15  = lane & 15;
    const int wr = wave >> 1;        // 0..1  (64-row oc' half)
    const int wc = wave & 1;         // 0..1  (32-col px half)
    const int px0 = blockIdx.x * 64;
    const int oc0 = blockIdx.y * 128;

    // A staging: 128 rows x 8 segs = 1024 tasks -> 4 rounds of 256.
    // B staging: 64 rows x 8 segs = 512 tasks -> 2 rounds of 256.
    int a_off[4], s_off[2];
#pragma unroll
    for (int it = 0; it < 4; it++) {
        int idx = it * 256 + tid;
        int rr = idx >> 3, seg = idx & 7;
        int segx = seg ^ (rr & 7);            // global-side swizzle
        a_off[it] = (oc0 + rr) * ktot + segx * 8;
    }
#pragma unroll
    for (int it = 0; it < 2; it++) {
        int idx = it * 256 + tid;
        int rr = idx >> 3, seg = idx & 7;
        int segx = seg ^ (rr & 7);
        int px = px0 + rr;
        int b = px >> 12, p = px & 4095, y = p >> 6, x = p & 63;
        s_off[it] = ((b * PADW + y + 1) * PADW + (x + 1)) * HID + segx * 8;
    }
    const int ldsbase = (tid & ~63) * 8;      // wave-uniform
    const int xa = l15 & 7;                   // read-side swizzle (= row&7)

    f32x4 acc[4][2] = {};
    const int nchunks = n0 + 9;

    auto stage_A = [&](int kk) {
        int ka = kk * 64;
#pragma unroll
        for (int it = 0; it < 4; it++)
            __builtin_amdgcn_global_load_lds(
                (const __attribute__((address_space(1))) void*)(Bw + a_off[it] + ka),
                (__attribute__((address_space(3))) void*)(&As[it * 2048 + ldsbase]),
                16, 0, 0);
    };
    auto stage_B = [&](int kk, int buf) {
        const __hip_bfloat16* src;
        int tap;
        if (kk < n0) { src = src0; tap = (n0 == 1) ? 4 : kk; }
        else         { src = src1; tap = kk - n0; }
        int dd = ((tap / 3) - 1) * (PADW * HID) + ((tap % 3) - 1) * HID;
#pragma unroll
        for (int it = 0; it < 2; it++)
            __builtin_amdgcn_global_load_lds(
                (const __attribute__((address_space(1))) void*)(src + s_off[it] + dd),
                (__attribute__((address_space(3))) void*)(&Bs[buf][it * 2048 + ldsbase]),
                16, 0, 0);
    };

    stage_B(0, 0);
    int cur = 0;
    for (int kk = 0; kk < nchunks; kk++) {
        stage_A(kk);                          // As free: all reads fenced by prev barrier2
        if (kk + 1 < nchunks) {
            stage_B(kk + 1, cur ^ 1);         // prefetch next h-tile
            // Wait for all but the 2 newest (the prefetch): A(kk)+B(kk) done.
            asm volatile("s_waitcnt vmcnt(2)" ::: "memory");
        } else {
            asm volatile("s_waitcnt vmcnt(0)" ::: "memory");
        }
        __builtin_amdgcn_sched_barrier(0);
        asm volatile("s_barrier" ::: "memory");   // raw: no vmcnt(0) drain
#pragma unroll
        for (int k2 = 0; k2 < 2; k2++) {
            int sA = ((k2 * 4 + quad) ^ xa) * 8;
            bf16x8 af[4], bfr[2];
#pragma unroll
            for (int i = 0; i < 4; i++)
                af[i] = *(const bf16x8*)&As[(wr * 64 + i * 16 + l15) * 64 + sA];
#pragma unroll
            for (int j = 0; j < 2; j++)
                bfr[j] = *(const bf16x8*)&Bs[cur][(wc * 32 + j * 16 + l15) * 64 + sA];
#pragma unroll
            for (int i = 0; i < 4; i++)
#pragma unroll
                for (int j = 0; j < 2; j++)
                    acc[i][j] = __builtin_amdgcn_mfma_f32_16x16x32_bf16(
                        af[i], bfr[j], acc[i][j], 0, 0, 0);
        }
        asm volatile("s_barrier" ::: "memory");   // protect As/Bs[cur] before overwrite
        cur ^= 1;
    }

    // ---- Epilogue ----------------------------------------------------------
    // Lane (quad,l15) of wave (wr,wc), tile (i,j): reg r = gate,
    // hid = oc'/4, px = col. Cell update in-register; h staged via LDS
    // (stride 40 to break bank conflicts) for coalesced NHWC stores.
    short* hl = As;                       // reuse: all LDS reads fenced above
    const int hid0 = oc0 >> 2;            // 0 or 32
#pragma unroll
    for (int i = 0; i < 4; i++) {
        int hidl = wr * 16 + i * 4 + quad;       // 0..31
        int hid = hid0 + hidl;
#pragma unroll
        for (int j = 0; j < 2; j++) {
            int pxl = wc * 32 + j * 16 + l15;    // 0..63
            int px = px0 + pxl;
            int b = px >> 12, p = px & 4095;
            size_t ci = ((size_t)(b * HID + hid)) * HW + p;
            float cv = first ? 0.0f : cbuf[ci];
            bf16x8 wv = *(const bf16x8*)&wcb[((size_t)hid * HW + p) * 8];
            float pg[4];
#pragma unroll
            for (int r = 0; r < 4; r++)
                pg[r] = acc[i][j][r] + bf2f(wv[r]) * cv + bf2f(wv[4 + r]);
            float ig = sigmoidf_(pg[0]);
            float fg = sigmoidf_(pg[1]);
            float gg = tanh_fast(pg[2]);
            float og = sigmoidf_(pg[3]);
            float cn = fg * cv + ig * gg;
            cbuf[ci] = cn;
            float hn = og * tanh_fast(cn);
            hl[pxl * 40 + hidl] = f2bf(hn);
        }
    }
    __syncthreads();
    {
        int task = tid;                          // 64 px x 4 q = 256 tasks
        int pxl = task >> 2, q = task & 3;
        bf16x8 v = *(const bf16x8*)&hl[pxl * 40 + q * 8];
        int px = px0 + pxl;
        int b = px >> 12, p = px & 4095, y = p >> 6, x = p & 63;
        *(bf16x8*)&hout[((size_t)((b * PADW + y + 1) * PADW + (x + 1))) * HID
                        + hid0 + q * 8] = v;
    }
}

// ---------------------------------------------------------------------------
// Final 1-out-channel 3x3 conv + sigmoid over packed bf16 h (padded NHWC).
// 256 blocks x 128 threads: covers all 256 CUs. Separate kernel: cannot
// perturb the gemm kernel's regalloc (round-4 lesson).
__global__ __launch_bounds__(128) void final_conv(
    const __hip_bfloat16* __restrict__ ph, const float* __restrict__ fw,
    const float* __restrict__ fb, float* __restrict__ out, int f) {
    int b = blockIdx.y;
    int p = blockIdx.x * 128 + threadIdx.x;
    int y = p >> 6, x = p & 63;
    float acc = fb[0];
#pragma unroll
    for (int tap = 0; tap < 9; tap++) {
        const bf16x8* base = (const bf16x8*)(
            ph + ((b * PADW + y + (tap / 3)) * PADW + (x + (tap % 3))) * HID);
#pragma unroll
        for (int c8 = 0; c8 < 8; c8++) {
            bf16x8 v = base[c8];
#pragma unroll
            for (int jj = 0; jj < 8; jj++)
                acc = fmaf(bf2f(v[jj]), fw[(c8 * 8 + jj) * 9 + tap], acc);
        }
    }
    out[((size_t)(b * FLEN + f)) * HW + p] = sigmoidf_(acc);
}

// ---------------------------------------------------------------------------
extern "C" void kernel_launch(void* const* d_in, const int* in_sizes, int n_in,
                              void* d_out, int out_size, void* d_ws, size_t ws_size,
                              hipStream_t stream) {
    const float* x = (const float*)d_in[0];
    const float* Wx_[4] = {(const float*)d_in[1], (const float*)d_in[5],
                           (const float*)d_in[9], (const float*)d_in[13]};
    const float* Wh_[4] = {(const float*)d_in[2], (const float*)d_in[6],
                           (const float*)d_in[10], (const float*)d_in[14]};
    const float* Wc_[4] = {(const float*)d_in[3], (const float*)d_in[7],
                           (const float*)d_in[11], (const float*)d_in[15]};
    const float* b_[4]  = {(const float*)d_in[4], (const float*)d_in[8],
                           (const float*)d_in[12], (const float*)d_in[16]};
    const float* fin_w  = (const float*)d_in[17];
    const float* fin_b  = (const float*)d_in[18];
    float* out = (float*)d_out;

    // Workspace layout:
    //   [8 h double-buffers bf16]  (memset to 0: initial states + halo rings)
    //   [10 px_all bf16]           (written by pack_x_all; poison elsewhere ok)
    //   [4 c states fp32]          (FIRST kernels don't read)
    //   [4 wcb bf16]  [4 Bw bf16]
    char* wsb = (char*)d_ws;
    const size_t H_BYTES  = 8ull * PADSZ * sizeof(short);       // 35,684,352
    const size_t PX_BYTES = 10ull * PADSZ * sizeof(short);      // 44,605,440
    const size_t C_BYTES  = 4ull * SB * sizeof(float);          // 33,554,432
    const size_t WCB_ELEM = (size_t)HID * HW * 8;               // per cell

    __hip_bfloat16* hb = (__hip_bfloat16*)wsb;
    __hip_bfloat16* px_all = (__hip_bfloat16*)(wsb + H_BYTES);
    float* cbuf = (float*)(wsb + H_BYTES + PX_BYTES);
    __hip_bfloat16* wcb = (__hip_bfloat16*)(wsb + H_BYTES + PX_BYTES + C_BYTES);
    __hip_bfloat16* bw = wcb + 4 * WCB_ELEM;

    __hip_bfloat16* e0buf[2] = {hb + 0 * (size_t)PADSZ, hb + 1 * (size_t)PADSZ};
    __hip_bfloat16* e1buf[2] = {hb + 2 * (size_t)PADSZ, hb + 3 * (size_t)PADSZ};
    __hip_bfloat16* d0buf[2] = {hb + 4 * (size_t)PADSZ, hb + 5 * (size_t)PADSZ};
    __hip_bfloat16* d1buf[2] = {hb + 6 * (size_t)PADSZ, hb + 7 * (size_t)PADSZ};

    float* ec0 = cbuf + 0 * (size_t)SB;
    float* ec1 = cbuf + 1 * (size_t)SB;
    float* dc0 = cbuf + 2 * (size_t)SB;
    float* dc1 = cbuf + 3 * (size_t)SB;

    __hip_bfloat16* wcb_[4] = {wcb, wcb + WCB_ELEM, wcb + 2 * WCB_ELEM, wcb + 3 * WCB_ELEM};
    __hip_bfloat16* bw_e0 = bw;
    __hip_bfloat16* bw_e1 = bw_e0 + (size_t)OC4 * KT_E0;
    __hip_bfloat16* bw_d0 = bw_e1 + (size_t)OC4 * KT_STD;
    __hip_bfloat16* bw_d1 = bw_d0 + (size_t)OC4 * KT_STD;
    __hip_bfloat16* bw_[4] = {bw_e0, bw_e1, bw_d0, bw_d1};
    float* c_[4] = {ec0, ec1, dc0, dc1};

    hipMemsetAsync(wsb, 0, H_BYTES, stream);

    reorder_w<<<dim3(OC4), 256, 0, stream>>>(Wx_[0], 1,   Wh_[0], bw_e0, KT_E0);
    reorder_w<<<dim3(OC4), 256, 0, stream>>>(Wx_[1], HID, Wh_[1], bw_e1, KT_STD);
    reorder_w<<<dim3(OC4), 256, 0, stream>>>(Wx_[2], HID, Wh_[2], bw_d0, KT_STD);
    reorder_w<<<dim3(OC4), 256, 0, stream>>>(Wx_[3], HID, Wh_[3], bw_d1, KT_STD);
    for (int cix = 0; cix < 4; cix++)
        pack_wcb<<<dim3((HID * HW) / 256), 256, 0, stream>>>(Wc_[cix], b_[cix], wcb_[cix]);
    pack_x_all<<<dim3((TSTEPS * BSZ * PPIX + 255) / 256), 256, 0, stream>>>(x, px_all);

    auto cellargs = [&](int cell, const __hip_bfloat16* s0, const __hip_bfloat16* s1,
                        __hip_bfloat16* ho, int kt, int nn0, int fi) {
        CellArgs a;
        a.Bw = bw_[cell]; a.src0 = s0; a.src1 = s1; a.wcb = wcb_[cell];
        a.cbuf = c_[cell]; a.hout = ho; a.ktot = kt; a.n0 = nn0; a.first = fi;
        return a;
    };
    auto px = [&](int t) { return px_all + (size_t)t * PADSZ; };

    dim3 gfin(32, BSZ);

    // --- Encoder, software-pipelined: dispatch k runs enc0(t=k) || enc1(t=k-1).
    // e0h(t) lives in e0buf[t&1]; e1h(t) in e1buf[t&1]; t=-1 state = zeros in buf[1].
    {
        CellArgs a = cellargs(0, px(0), e0buf[1], e0buf[0], KT_E0, 1, 1);
        gemm_cell_fused<<<dim3(512, 2, 1), 256, 0, stream>>>(a, a);
    }
    for (int k = 1; k <= 9; k++) {
        int t0 = k, t1 = k - 1;
        CellArgs a0 = cellargs(0, px(t0), e0buf[(t0 - 1) & 1], e0buf[t0 & 1],
                               KT_E0, 1, 0);
        CellArgs a1 = cellargs(1, e0buf[t1 & 1], e1buf[(t1 - 1) & 1], e1buf[t1 & 1],
                               KT_STD, 9, (t1 == 0) ? 1 : 0);
        gemm_cell_fused<<<dim3(512, 2, 2), 256, 0, stream>>>(a0, a1);
    }
    {
        CellArgs a = cellargs(1, e0buf[1], e1buf[0], e1buf[1], KT_STD, 9, 0); // t=9
        gemm_cell_fused<<<dim3(512, 2, 1), 256, 0, stream>>>(a, a);
    }
    __hip_bfloat16* enc_top = e1buf[1];   // e1h(9)

    // --- Decoder (strictly sequential chain)
    for (int f = 0; f < FLEN; f++) {
        const __hip_bfloat16* s = (f == 0) ? enc_top : d1buf[(f - 1) & 1];
        CellArgs a0 = cellargs(2, s, d0buf[(f - 1) & 1], d0buf[f & 1],
                               KT_STD, 9, (f == 0) ? 1 : 0);
        gemm_cell_fused<<<dim3(512, 2, 1), 256, 0, stream>>>(a0, a0);
        CellArgs a1 = cellargs(3, d0buf[f & 1], d1buf[(f - 1) & 1], d1buf[f & 1],
                               KT_STD, 9, (f == 0) ? 1 : 0);
        gemm_cell_fused<<<dim3(512, 2, 1), 256, 0, stream>>>(a1, a1);
        final_conv<<<gfin, 128, 0, stream>>>(d1buf[f & 1], fin_w, fin_b, out, f);
    }
}